// Round 3
// baseline (137.908 us; speedup 1.0000x reference)
//
#include <hip/hip_runtime.h>
#include <math.h>

#define Nn 8192
#define Dd 256
#define Kk 32

// ws float layout:
// [0,      8192)   u4T : w transposed [d4][k][4]
// [8192,  16384)   v4T : (w*b) transposed, same layout
// [16384, 24576)   G[k][d]
// [24576, 32768)   H[k][d]
// [32768, 32800)   S[k]
// [32832, 294976)  gam[n][k]  (8192*32 floats = 1 MB)
#define GAM_OFF 32832

__global__ __launch_bounds__(256) void prep_kernel(const float* __restrict__ w,
                                                   const float* __restrict__ b,
                                                   float* __restrict__ ws) {
    int k = blockIdx.x, d = threadIdx.x;
    float wv = w[k * Dd + d];
    float bv = b[k * Dd + d];
    int gi = ((d >> 2) * Kk + k) * 4 + (d & 3);
    ws[gi]        = wv;        // u4T
    ws[8192 + gi] = wv * bv;   // v4T
    ws[16384 + k * Dd + d] = 0.f;  // G
    ws[24576 + k * Dd + d] = 0.f;  // H
    if (k == 0 && d < Kk) ws[32768 + d] = 0.f;  // S
}

// One wave processes 4 rows (register-blocked for u/v reuse). No barriers
// after the initial staging; softmax via 32-lane shuffles.
__global__ __launch_bounds__(256) void gamma_kernel(const float* __restrict__ x,
                                                    float* __restrict__ ws) {
    __shared__ __align__(16) float uS[8192];   // 32 KB
    __shared__ __align__(16) float vS[8192];   // 32 KB
    __shared__ __align__(16) float xS[4096];   // 16 KB: 16 rows x 256
    float* gamG = ws + GAM_OFF;
    float* S = ws + 32768;

    int tid = threadIdx.x;
    {
        const float4* u4 = (const float4*)ws;
        const float4* v4 = (const float4*)(ws + 8192);
        float4* uD = (float4*)uS;
        float4* vD = (float4*)vS;
        #pragma unroll
        for (int i = 0; i < 8; ++i) {
            uD[tid + 256 * i] = u4[tid + 256 * i];
            vD[tid + 256 * i] = v4[tid + 256 * i];
        }
        const float4* xg = (const float4*)(x + (size_t)blockIdx.x * 16 * Dd);
        float4* xD = (float4*)xS;
        #pragma unroll
        for (int i = 0; i < 4; ++i) xD[tid + 256 * i] = xg[tid + 256 * i];
    }
    __syncthreads();

    int lane = tid & 63;
    int wave = tid >> 6;
    int k = lane & 31;
    int h = lane >> 5;
    int r0 = wave * 4;                      // local row base (4 rows per wave)

    const float4* uS4 = (const float4*)uS;
    const float4* vS4 = (const float4*)vS;
    const float4* xS4 = (const float4*)xS;

    float4 a0 = {0.f,0.f,0.f,0.f}, a1 = a0, a2 = a0, a3 = a0;

    #pragma unroll 4
    for (int i = 0; i < 32; ++i) {
        int ii = h * 32 + i;
        float4 u = uS4[ii * 32 + k];
        float4 v = vS4[ii * 32 + k];
        float4 x0 = xS4[(r0 + 0) * 64 + ii];   // LDS broadcast
        float4 x1 = xS4[(r0 + 1) * 64 + ii];
        float4 x2 = xS4[(r0 + 2) * 64 + ii];
        float4 x3 = xS4[(r0 + 3) * 64 + ii];
        float y;
        y = fmaf(u.x, x0.x, v.x); a0.x = fmaf(y, y, a0.x);
        y = fmaf(u.y, x0.y, v.y); a0.y = fmaf(y, y, a0.y);
        y = fmaf(u.z, x0.z, v.z); a0.z = fmaf(y, y, a0.z);
        y = fmaf(u.w, x0.w, v.w); a0.w = fmaf(y, y, a0.w);
        y = fmaf(u.x, x1.x, v.x); a1.x = fmaf(y, y, a1.x);
        y = fmaf(u.y, x1.y, v.y); a1.y = fmaf(y, y, a1.y);
        y = fmaf(u.z, x1.z, v.z); a1.z = fmaf(y, y, a1.z);
        y = fmaf(u.w, x1.w, v.w); a1.w = fmaf(y, y, a1.w);
        y = fmaf(u.x, x2.x, v.x); a2.x = fmaf(y, y, a2.x);
        y = fmaf(u.y, x2.y, v.y); a2.y = fmaf(y, y, a2.y);
        y = fmaf(u.z, x2.z, v.z); a2.z = fmaf(y, y, a2.z);
        y = fmaf(u.w, x2.w, v.w); a2.w = fmaf(y, y, a2.w);
        y = fmaf(u.x, x3.x, v.x); a3.x = fmaf(y, y, a3.x);
        y = fmaf(u.y, x3.y, v.y); a3.y = fmaf(y, y, a3.y);
        y = fmaf(u.z, x3.z, v.z); a3.z = fmaf(y, y, a3.z);
        y = fmaf(u.w, x3.w, v.w); a3.w = fmaf(y, y, a3.w);
    }

    float s0 = (a0.x + a0.y) + (a0.z + a0.w);
    float s1 = (a1.x + a1.y) + (a1.z + a1.w);
    float s2 = (a2.x + a2.y) + (a2.z + a2.w);
    float s3 = (a3.x + a3.y) + (a3.z + a3.w);
    s0 += __shfl_xor(s0, 32);
    s1 += __shfl_xor(s1, 32);
    s2 += __shfl_xor(s2, 32);
    s3 += __shfl_xor(s3, 32);
    float y40 = -0.5f * s0, y41 = -0.5f * s1, y42 = -0.5f * s2, y43 = -0.5f * s3;

    float m0 = y40, m1 = y41, m2 = y42, m3 = y43;
    #pragma unroll
    for (int o = 16; o >= 1; o >>= 1) {
        m0 = fmaxf(m0, __shfl_xor(m0, o));
        m1 = fmaxf(m1, __shfl_xor(m1, o));
        m2 = fmaxf(m2, __shfl_xor(m2, o));
        m3 = fmaxf(m3, __shfl_xor(m3, o));
    }
    float e0 = __expf(y40 - m0), e1 = __expf(y41 - m1);
    float e2 = __expf(y42 - m2), e3 = __expf(y43 - m3);
    float t0 = e0, t1 = e1, t2 = e2, t3 = e3;
    #pragma unroll
    for (int o = 16; o >= 1; o >>= 1) {
        t0 += __shfl_xor(t0, o);
        t1 += __shfl_xor(t1, o);
        t2 += __shfl_xor(t2, o);
        t3 += __shfl_xor(t3, o);
    }
    float g0 = e0 / t0, g1 = e1 / t1, g2 = e2 / t2, g3 = e3 / t3;

    if (h == 0) {
        size_t row = (size_t)blockIdx.x * 16 + r0;
        gamG[(row + 0) * Kk + k] = g0;
        gamG[(row + 1) * Kk + k] = g1;
        gamG[(row + 2) * Kk + k] = g2;
        gamG[(row + 3) * Kk + k] = g3;
        atomicAdd(&S[k], (g0 + g1) + (g2 + g3));
    }
}

// Thread owns column d=tid; 64 independent register accumulators; x
// prefetched to registers; gamma chunk staged once. No barriers in the loop.
__global__ __launch_bounds__(256) void reduce_kernel(const float* __restrict__ x,
                                                     float* __restrict__ ws) {
    const float* gamG = ws + GAM_OFF;
    float* G = ws + 16384;
    float* H = ws + 24576;
    __shared__ __align__(16) float gamS[512];   // 16 rows x 32

    int tid = threadIdx.x;
    int base = blockIdx.x * 16;
    if (tid < 128)
        ((float4*)gamS)[tid] = ((const float4*)(gamG + (size_t)base * Kk))[tid];
    __syncthreads();

    float accg[32], acch[32];
    #pragma unroll
    for (int i = 0; i < 32; ++i) { accg[i] = 0.f; acch[i] = 0.f; }

    float xv[16];
    #pragma unroll
    for (int r = 0; r < 16; ++r) xv[r] = x[(size_t)(base + r) * Dd + tid];

    #pragma unroll
    for (int r = 0; r < 16; ++r) {
        float xa = xv[r];
        float xx = xa * xa;
        const float4* gr = (const float4*)(gamS + r * Kk);
        #pragma unroll
        for (int q = 0; q < 8; ++q) {
            float4 gv = gr[q];                 // LDS broadcast
            accg[4*q+0] = fmaf(gv.x, xa, accg[4*q+0]);
            acch[4*q+0] = fmaf(gv.x, xx, acch[4*q+0]);
            accg[4*q+1] = fmaf(gv.y, xa, accg[4*q+1]);
            acch[4*q+1] = fmaf(gv.y, xx, acch[4*q+1]);
            accg[4*q+2] = fmaf(gv.z, xa, accg[4*q+2]);
            acch[4*q+2] = fmaf(gv.z, xx, acch[4*q+2]);
            accg[4*q+3] = fmaf(gv.w, xa, accg[4*q+3]);
            acch[4*q+3] = fmaf(gv.w, xx, acch[4*q+3]);
        }
    }

    #pragma unroll
    for (int kk = 0; kk < 32; ++kk) {
        atomicAdd(&G[kk * Dd + tid], accg[kk]);
        atomicAdd(&H[kk * Dd + tid], acch[kk]);
    }
}

// grid MUST be 32 blocks: each thread handles one (k,d) pair and writes BOTH
// the sigma half (out[idx]) and the mu half (out[8192+idx]).
__global__ __launch_bounds__(256) void epi_kernel(const float* __restrict__ w,
                                                  const float* __restrict__ b,
                                                  const float* __restrict__ ws,
                                                  float* __restrict__ out) {
    int idx = blockIdx.x * 256 + threadIdx.x;   // 0..8191
    int k = idx >> 8;
    float Gv = ws[16384 + idx];
    float Hv = ws[24576 + idx];
    float sv = ws[32768 + k];
    float wv = w[idx], bv = b[idx];
    const float invN = 1.0f / 8192.0f;
    const float c2 = 0.70710678118654752440f * invN;  // 1/(sqrt(2)*N)
    float mu = wv * (Gv + bv * sv) * invN;
    float w2 = wv * wv;
    float sg = (w2 * (Hv + 2.0f * bv * Gv + bv * bv * sv) - sv) * c2;
    out[idx] = sg;             // sigma_part
    out[Kk * Dd + idx] = mu;   // mu_part
}

extern "C" void kernel_launch(void* const* d_in, const int* in_sizes, int n_in,
                              void* d_out, int out_size, void* d_ws, size_t ws_size,
                              hipStream_t stream) {
    const float* x = (const float*)d_in[0];
    const float* w = (const float*)d_in[1];
    const float* b = (const float*)d_in[2];
    float* out = (float*)d_out;
    float* ws = (float*)d_ws;

    hipLaunchKernelGGL(prep_kernel,   dim3(Kk),  dim3(256), 0, stream, w, b, ws);
    hipLaunchKernelGGL(gamma_kernel,  dim3(512), dim3(256), 0, stream, x, ws);
    hipLaunchKernelGGL(reduce_kernel, dim3(512), dim3(256), 0, stream, x, ws);
    hipLaunchKernelGGL(epi_kernel,    dim3(32),  dim3(256), 0, stream, w, b, ws, out);
}